// Round 1
// baseline (545.822 us; speedup 1.0000x reference)
//
#include <hip/hip_runtime.h>
#include <hip/hip_bf16.h>

#define IN_EPS 1e-5f

typedef __attribute__((ext_vector_type(8))) short short8;
typedef __attribute__((ext_vector_type(4))) float f32x4;

__device__ __forceinline__ short f2bf(float f) {
  union { float f; unsigned u; } x; x.f = f;
  unsigned r = x.u + 0x7fffu + ((x.u >> 16) & 1u);
  return (short)(r >> 16);
}

__device__ __forceinline__ void glds16(const void* g, void* l) {
  typedef const __attribute__((address_space(1))) void gconst_t;
  typedef __attribute__((address_space(3))) void lds_t;
  __builtin_amdgcn_global_load_lds((gconst_t*)g, (lds_t*)l, 16, 0, 0);
}

// ---------------------------------------------------------------------------
// Weight conversion: f32 [O][C][3][3] -> bf16 swizzled tile image
// layout: [mblk][kstep=36][o_local=128][kl=64], elem (o,kl) at
//   ((mblk*36+kstep)<<13) + (o<<6) + (kl ^ ((o&7)<<3))
// K-order: kappa = tap*256 + c
// ---------------------------------------------------------------------------
__global__ void wconv_k(const float* __restrict__ src, short* __restrict__ dst,
                        int O) {
  int idx = blockIdx.x * 256 + threadIdx.x;
  if (idx >= O * 2304) return;
  int o = idx / 2304;
  int r = idx - o * 2304;
  int c = r / 9;
  int k = r - c * 9;
  int kap = k * 256 + c;
  int mblk = o >> 7, ol = o & 127, kstep = kap >> 6, kl = kap & 63;
  dst[(((size_t)(mblk * 36 + kstep)) << 13) + (ol << 6) + (kl ^ ((ol & 7) << 3))]
      = f2bf(src[idx]);
}

// ---------------------------------------------------------------------------
// Adaptive Gaussian kernel: kern[b][k][h][w] = exp(-0.5 * sum_c dg^2)
// block = (h,b), 256 threads: 64 pixels x 4 channel-groups of 64
// ---------------------------------------------------------------------------
__global__ __launch_bounds__(256) void kern_k(const float* __restrict__ g,
                                              float* __restrict__ kern) {
  int h = blockIdx.x, b = blockIdx.y;
  int t = threadIdx.x, w = t & 63, cg = t >> 6;
  __shared__ float sm[4][3][66];
  __shared__ float red[4][9][64];
  if (t < 24) {  // zero halo columns (never rewritten)
    int cgi = t / 6, rem = t - cgi * 6, i = rem >> 1, side = rem & 1;
    sm[cgi][i][side ? 65 : 0] = 0.f;
  }
  float acc[9];
#pragma unroll
  for (int k = 0; k < 9; ++k) acc[k] = 0.f;

  for (int cc = 0; cc < 64; ++cc) {
    const float* gp = g + (((size_t)b * 256 + (cg << 6) + cc) << 12) + h * 64 + w;
    sm[cg][0][w + 1] = (h > 0) ? gp[-64] : 0.f;
    sm[cg][1][w + 1] = gp[0];
    sm[cg][2][w + 1] = (h < 63) ? gp[64] : 0.f;
    __syncthreads();
    float ctr = sm[cg][1][w + 1];
#pragma unroll
    for (int i = 0; i < 3; ++i)
#pragma unroll
      for (int j = 0; j < 3; ++j) {
        float d = sm[cg][i][w + j] - ctr;
        acc[i * 3 + j] += d * d;
      }
    __syncthreads();
  }
#pragma unroll
  for (int k = 0; k < 9; ++k) red[cg][k][w] = acc[k];
  __syncthreads();
  for (int idx = t; idx < 576; idx += 256) {
    int k = idx >> 6, w2 = idx & 63;
    float s = red[0][k][w2] + red[1][k][w2] + red[2][k][w2] + red[3][k][w2];
    kern[(((size_t)b * 9 + k) << 12) + h * 64 + w2] = expf(-0.5f * s);
  }
}

// ---------------------------------------------------------------------------
// Implicit-GEMM conv. BM=128, BN=128 (2 full rows), BK=64, 36 K-steps.
// A = swizzled bf16 weights (global_load_lds), B = reg-staged activations
// (optional kern multiply / instance-norm+relu fused), 4 waves, acc 64x64/wave
// ---------------------------------------------------------------------------
template <int MBLKS, bool USE_KERN, bool USE_NORM>
__global__ __launch_bounds__(256, 2) void gemm_conv(
    const short* __restrict__ Wsw, const float* __restrict__ X,
    const float* __restrict__ Kf, const float* __restrict__ MRin,
    float* __restrict__ out) {
  constexpr int NT = 36;
  constexpr int MOUT = MBLKS * 128;
  __shared__ short ldsA[2][8192];
  __shared__ short ldsB[2][8192];

  const int t = threadIdx.x;
  const int nblk = blockIdx.x, mblk = blockIdx.y, b = blockIdx.z;
  const int h0 = nblk * 2;
  const int lane = t & 63, wid = t >> 6;
  const int wr = wid >> 1, wc = wid & 1;
  const int p = t & 127, cq = t >> 7;  // B-staging: pixel, channel-half
  const int prow = p >> 6, w = p & 63;

  f32x4 acc[4][4];
#pragma unroll
  for (int i = 0; i < 4; ++i)
#pragma unroll
    for (int j = 0; j < 4; ++j) acc[i][j] = {0.f, 0.f, 0.f, 0.f};

  auto stageA = [&](int step, int buf) {
#pragma unroll
    for (int i = 0; i < 4; ++i) {
      int cb = (i << 8) + (wid << 6);
      glds16(Wsw + (((size_t)mblk * NT + step) << 13) + ((size_t)(cb + lane) << 3),
             &ldsA[buf][cb << 3]);
    }
  };
  auto loadB = [&](int step, float* vals) {
    int tap = step >> 2;
    int di = tap / 3 - 1, dj = tap % 3 - 1;
    int c0 = ((step & 3) << 6) + (cq << 5);
    int hh = h0 + prow + di, ww = w + dj;
    bool ok = ((unsigned)hh < 64u) && ((unsigned)ww < 64u);
    float kf = 1.f;
    if (USE_KERN) kf = Kf[(((size_t)b * 9 + tap) << 12) + (h0 + prow) * 64 + w];
    const float* src = X + (((size_t)b * 256 + c0) << 12) + hh * 64 + ww;
#pragma unroll
    for (int i = 0; i < 32; ++i) {
      float v = 0.f;
      if (ok) {
        v = src[(size_t)i << 12];
        if (USE_NORM) {
          float2 mr = ((const float2*)MRin)[b * 256 + c0 + i];
          v = fmaxf((v - mr.x) * mr.y, 0.f);
        }
        if (USE_KERN) v *= kf;
      }
      vals[i] = v;
    }
  };
  auto packB = [&](const float* vals, int buf) {
#pragma unroll
    for (int q = 0; q < 4; ++q) {
      short8 pk;
#pragma unroll
      for (int i = 0; i < 8; ++i) pk[i] = f2bf(vals[q * 8 + i]);
      int kl = (cq << 5) + (q << 3);
      int off = (p << 6) + (kl ^ ((p & 7) << 3));
      *(short8*)(&ldsB[buf][off]) = pk;
    }
  };
  auto compute = [&](int buf) {
    const short* As = ldsA[buf];
    const short* Bs = ldsB[buf];
    int kgrp = (lane >> 4) << 3;
    int fr = lane & 15;
#pragma unroll
    for (int ks = 0; ks < 2; ++ks) {
      int kb = (ks << 5) + kgrp;
      short8 af[4], bfr[4];
#pragma unroll
      for (int mf = 0; mf < 4; ++mf) {
        int r = (wr << 6) + (mf << 4) + fr;
        af[mf] = *(const short8*)(As + (r << 6) + (kb ^ ((r & 7) << 3)));
      }
#pragma unroll
      for (int nf = 0; nf < 4; ++nf) {
        int pc = (wc << 6) + (nf << 4) + fr;
        bfr[nf] = *(const short8*)(Bs + (pc << 6) + (kb ^ ((pc & 7) << 3)));
      }
#pragma unroll
      for (int mf = 0; mf < 4; ++mf)
#pragma unroll
        for (int nf = 0; nf < 4; ++nf)
          acc[mf][nf] = __builtin_amdgcn_mfma_f32_16x16x32_bf16(
              af[mf], bfr[nf], acc[mf][nf], 0, 0, 0);
    }
  };

  {
    float vals[32];
    stageA(0, 0);
    loadB(0, vals);
    packB(vals, 0);
  }
  __syncthreads();
  int cur = 0;
  for (int step = 0; step < NT; ++step) {
    int nxt = cur ^ 1;
    float vals[32];
    bool have = (step + 1) < NT;
    if (have) {
      stageA(step + 1, nxt);
      loadB(step + 1, vals);
    }
    compute(cur);
    if (have) packB(vals, nxt);
    __syncthreads();
    cur = nxt;
  }

  const int row4 = (lane >> 4) << 2;
  const int colf = lane & 15;
#pragma unroll
  for (int mf = 0; mf < 4; ++mf) {
    int o = (mblk << 7) + (wr << 6) + (mf << 4) + row4;
    size_t obase = (((size_t)b * MOUT + o) << 12) + (nblk << 7) + (wc << 6) + colf;
#pragma unroll
    for (int nf = 0; nf < 4; ++nf) {
      f32x4 v = acc[mf][nf];
      size_t ob = obase + (nf << 4);
      out[ob] = v[0];
      out[ob + 4096] = v[1];
      out[ob + 8192] = v[2];
      out[ob + 12288] = v[3];
    }
  }
}

// ---------------------------------------------------------------------------
// per-(b,ch) mean / rstd over 4096 pixels
// ---------------------------------------------------------------------------
__global__ __launch_bounds__(256) void reduce_mv(const float* __restrict__ x,
                                                 float* __restrict__ mr) {
  int bc = blockIdx.x, t = threadIdx.x;
  const float4* xp = (const float4*)(x + ((size_t)bc << 12));
  float s = 0.f, s2 = 0.f;
  for (int i = t; i < 1024; i += 256) {
    float4 v = xp[i];
    s += v.x + v.y + v.z + v.w;
    s2 += v.x * v.x + v.y * v.y + v.z * v.z + v.w * v.w;
  }
#pragma unroll
  for (int off = 32; off; off >>= 1) {
    s += __shfl_down(s, off);
    s2 += __shfl_down(s2, off);
  }
  __shared__ float ls[4], ls2[4];
  int wid = t >> 6, lane = t & 63;
  if (!lane) { ls[wid] = s; ls2[wid] = s2; }
  __syncthreads();
  if (!t) {
    s = ls[0] + ls[1] + ls[2] + ls[3];
    s2 = ls2[0] + ls2[1] + ls2[2] + ls2[3];
    float m = s * (1.f / 4096.f);
    float var = s2 * (1.f / 4096.f) - m * m;
    mr[2 * bc] = m;
    mr[2 * bc + 1] = rsqrtf(fmaxf(var, 0.f) + IN_EPS);
  }
}

// ---------------------------------------------------------------------------
// out = relu((y - mean)*rstd), float4 over [8*128*4096]
// ---------------------------------------------------------------------------
__global__ __launch_bounds__(256) void finalize_k(const float* __restrict__ y,
                                                  const float* __restrict__ mr,
                                                  float* __restrict__ out) {
  int i = blockIdx.x * 256 + threadIdx.x;  // exactly 1,048,576 threads
  int bc = i >> 10;
  float m = mr[2 * bc], r = mr[2 * bc + 1];
  float4 v = ((const float4*)y)[i];
  v.x = fmaxf((v.x - m) * r, 0.f);
  v.y = fmaxf((v.y - m) * r, 0.f);
  v.z = fmaxf((v.z - m) * r, 0.f);
  v.w = fmaxf((v.w - m) * r, 0.f);
  ((float4*)out)[i] = v;
}

extern "C" void kernel_launch(void* const* d_in, const int* in_sizes, int n_in,
                              void* d_out, int out_size, void* d_ws,
                              size_t ws_size, hipStream_t stream) {
  (void)in_sizes; (void)n_in; (void)out_size; (void)ws_size;
  const float* feat  = (const float*)d_in[0];
  const float* guide = (const float*)d_in[1];
  const float* pac_w = (const float*)d_in[2];
  const float* dec_w = (const float*)d_in[3];
  // d_in[4] (dec_b) intentionally unused: constant per-channel bias cancels
  // in the following InstanceNorm (mean subtraction).
  float* out = (float*)d_out;
  char* ws = (char*)d_ws;

  float* kernbuf = (float*)(ws);                 // 8*9*4096*4   = 0x120000
  short* Ws1     = (short*)(ws + 0x120000);      // 2*36*8192*2  = 0x120000
  short* Ws2     = (short*)(ws + 0x240000);      // 1*36*8192*2  = 0x090000
  float* mr1     = (float*)(ws + 0x2D0000);      // 2048*2*4     = 0x4000
  float* mr2     = (float*)(ws + 0x2D4000);      // 1024*2*4     = 0x2000
  float* pac     = (float*)(ws + 0x300000);      // 8*256*4096*4 = 0x2000000
  float* ybuf    = (float*)(ws + 0x2300000);     // 8*128*4096*4 = 0x1000000

  wconv_k<<<(256 * 2304 + 255) / 256, 256, 0, stream>>>(pac_w, Ws1, 256);
  wconv_k<<<(128 * 2304 + 255) / 256, 256, 0, stream>>>(dec_w, Ws2, 128);
  kern_k<<<dim3(64, 8), 256, 0, stream>>>(guide, kernbuf);

  gemm_conv<2, true, false><<<dim3(32, 2, 8), 256, 0, stream>>>(
      Ws1, feat, kernbuf, nullptr, pac);
  reduce_mv<<<8 * 256, 256, 0, stream>>>(pac, mr1);
  gemm_conv<1, false, true><<<dim3(32, 1, 8), 256, 0, stream>>>(
      Ws2, pac, nullptr, mr1, ybuf);
  reduce_mv<<<8 * 128, 256, 0, stream>>>(ybuf, mr2);
  finalize_k<<<4096, 256, 0, stream>>>(ybuf, mr2, out);
}

// Round 2
// 266.676 us; speedup vs baseline: 2.0468x; 2.0468x over previous
//
#include <hip/hip_runtime.h>
#include <hip/hip_bf16.h>

#define IN_EPS 1e-5f

typedef __attribute__((ext_vector_type(8))) short short8;
typedef __attribute__((ext_vector_type(4))) float f32x4;

__device__ __forceinline__ short f2bf(float f) {
  __hip_bfloat16 h = (__hip_bfloat16)f;   // compiler lowers to v_cvt_pk_bf16_f32
  return *(short*)&h;
}

__device__ __forceinline__ void glds16(const void* g, void* l) {
  typedef const __attribute__((address_space(1))) void gconst_t;
  typedef __attribute__((address_space(3))) void lds_t;
  __builtin_amdgcn_global_load_lds((gconst_t*)g, (lds_t*)l, 16, 0, 0);
}

// ---------------------------------------------------------------------------
// Weight conversion: f32 [O][C][3][3] -> bf16 swizzled tile image
// layout: [mblk][kstep=36][o_local=128][kl=64], elem (o,kl) at
//   ((mblk*36+kstep)<<13) + (o<<6) + (kl ^ ((o&7)<<3))
// K-order: kappa = tap*256 + c
// ---------------------------------------------------------------------------
__global__ void wconv_k(const float* __restrict__ src, short* __restrict__ dst,
                        int O) {
  int idx = blockIdx.x * 256 + threadIdx.x;
  if (idx >= O * 2304) return;
  int o = idx / 2304;
  int r = idx - o * 2304;
  int c = r / 9;
  int k = r - c * 9;
  int kap = k * 256 + c;
  int mblk = o >> 7, ol = o & 127, kstep = kap >> 6, kl = kap & 63;
  dst[(((size_t)(mblk * 36 + kstep)) << 13) + (ol << 6) + (kl ^ ((ol & 7) << 3))]
      = f2bf(src[idx]);
}

// ---------------------------------------------------------------------------
// Adaptive Gaussian kernel: kern[b][k][h][w] = exp(-0.5 * sum_c dg^2)
// ---------------------------------------------------------------------------
__global__ __launch_bounds__(256) void kern_k(const float* __restrict__ g,
                                              float* __restrict__ kern) {
  int h = blockIdx.x, b = blockIdx.y;
  int t = threadIdx.x, w = t & 63, cg = t >> 6;
  __shared__ float sm[4][3][66];
  __shared__ float red[4][9][64];
  if (t < 24) {
    int cgi = t / 6, rem = t - cgi * 6, i = rem >> 1, side = rem & 1;
    sm[cgi][i][side ? 65 : 0] = 0.f;
  }
  float acc[9];
#pragma unroll
  for (int k = 0; k < 9; ++k) acc[k] = 0.f;

  for (int cc = 0; cc < 64; ++cc) {
    const float* gp = g + (((size_t)b * 256 + (cg << 6) + cc) << 12) + h * 64 + w;
    sm[cg][0][w + 1] = (h > 0) ? gp[-64] : 0.f;
    sm[cg][1][w + 1] = gp[0];
    sm[cg][2][w + 1] = (h < 63) ? gp[64] : 0.f;
    __syncthreads();
    float ctr = sm[cg][1][w + 1];
#pragma unroll
    for (int i = 0; i < 3; ++i)
#pragma unroll
      for (int j = 0; j < 3; ++j) {
        float d = sm[cg][i][w + j] - ctr;
        acc[i * 3 + j] += d * d;
      }
    __syncthreads();
  }
#pragma unroll
  for (int k = 0; k < 9; ++k) red[cg][k][w] = acc[k];
  __syncthreads();
  for (int idx = t; idx < 576; idx += 256) {
    int k = idx >> 6, w2 = idx & 63;
    float s = red[0][k][w2] + red[1][k][w2] + red[2][k][w2] + red[3][k][w2];
    kern[(((size_t)b * 9 + k) << 12) + h * 64 + w2] = expf(-0.5f * s);
  }
}

// ---------------------------------------------------------------------------
// Implicit-GEMM conv. BM=128, BN=128|64, BK=64, 36 K-steps, 512 thr / 8 waves.
// Wave grid 2(M)x4(N): per-wave 64M x BN/4 N, acc[4][BN/64].
// A = pre-swizzled bf16 weights via global_load_lds; B = reg-staged f32
// activations (kern-mul / instance-norm+relu fused), bf16-packed, XOR-swizzled.
// ---------------------------------------------------------------------------
template <int MBLKS, int BN, bool USE_KERN, bool USE_NORM>
__global__ __launch_bounds__(512, 4) void gemm_conv(
    const short* __restrict__ Wsw, const float* __restrict__ X,
    const float* __restrict__ Kf, const float* __restrict__ MRin,
    float* __restrict__ out) {
  constexpr int NT = 36;
  constexpr int MOUT = MBLKS * 128;
  constexpr int EL = BN / 8;    // B elems per thread (16 or 8)
  constexpr int NF = BN / 64;   // B frags per wave (2 or 1)
  constexpr int ROWS = BN / 64; // image rows per tile
  constexpr int WN = BN / 4;    // N per wave
  __shared__ short ldsA[2][8192];
  __shared__ short ldsB[2][BN * 64];

  const int t = threadIdx.x;
  const int nblk = blockIdx.x, mblk = blockIdx.y, b = blockIdx.z;
  const int h0 = nblk * ROWS;
  const int lane = t & 63, wid = t >> 6;
  const int wr = wid >> 2, wc = wid & 3;
  const int px = t & (BN - 1), g = t / BN;   // B staging: pixel, kappa-group
  const int kbase = g * EL;
  const int prow = (ROWS == 2) ? (px >> 6) : 0;
  const int w = px & 63;

  f32x4 acc[4][NF];
#pragma unroll
  for (int i = 0; i < 4; ++i)
#pragma unroll
    for (int j = 0; j < NF; ++j) acc[i][j] = {0.f, 0.f, 0.f, 0.f};

  float vls[EL];

  auto stageA = [&](int step, int buf) {
#pragma unroll
    for (int i = 0; i < 2; ++i) {
      int chunk = (i << 3) + wid;  // 16 x 1KB chunks
      glds16(Wsw + (((size_t)(mblk * NT + step)) << 13) + (chunk << 9) + (lane << 3),
             &ldsA[buf][chunk << 9]);
    }
  };
  auto loadB = [&](int step) {
    int tap = step >> 2, cq = step & 3;
    int di = tap / 3 - 1, dj = tap % 3 - 1;
    int c0 = (cq << 6) + kbase;
    int hh = h0 + prow + di, ww = w + dj;
    bool ok = ((unsigned)hh < 64u) && ((unsigned)ww < 64u);
    float kf = 1.f;
    if (USE_KERN) kf = Kf[(((size_t)b * 9 + tap) << 12) + ((h0 + prow) << 6) + w];
    const float* src = X + (((size_t)b * 256 + c0) << 12) + hh * 64 + ww;
#pragma unroll
    for (int i = 0; i < EL; ++i) {
      float v = 0.f;
      if (ok) {
        v = src[(size_t)i << 12];
        if (USE_NORM) {
          float2 mr = ((const float2*)MRin)[b * 256 + c0 + i];
          v = fmaxf((v - mr.x) * mr.y, 0.f);
        }
        if (USE_KERN) v *= kf;
      }
      vls[i] = v;
    }
  };
  auto packB = [&](int buf) {
#pragma unroll
    for (int q = 0; q < EL / 8; ++q) {
      short8 pk;
#pragma unroll
      for (int i = 0; i < 8; ++i) pk[i] = f2bf(vls[q * 8 + i]);
      int kl = kbase + (q << 3);
      *(short8*)(&ldsB[buf][(px << 6) + (kl ^ ((px & 7) << 3))]) = pk;
    }
  };
  auto compute = [&](int buf) {
    int fr = lane & 15, kg = (lane >> 4) << 3;
#pragma unroll
    for (int ks = 0; ks < 2; ++ks) {
      int kb = (ks << 5) + kg;
      short8 af[4], bfr[NF];
#pragma unroll
      for (int mf = 0; mf < 4; ++mf) {
        int r = (wr << 6) + (mf << 4) + fr;
        af[mf] = *(const short8*)(&ldsA[buf][(r << 6) + (kb ^ ((r & 7) << 3))]);
      }
#pragma unroll
      for (int nf = 0; nf < NF; ++nf) {
        int pc = wc * WN + (nf << 4) + fr;
        bfr[nf] = *(const short8*)(&ldsB[buf][(pc << 6) + (kb ^ ((pc & 7) << 3))]);
      }
#pragma unroll
      for (int mf = 0; mf < 4; ++mf)
#pragma unroll
        for (int nf = 0; nf < NF; ++nf)
          acc[mf][nf] = __builtin_amdgcn_mfma_f32_16x16x32_bf16(
              af[mf], bfr[nf], acc[mf][nf], 0, 0, 0);
    }
  };

  stageA(0, 0);
  loadB(0);
  packB(0);
  __syncthreads();
  int cur = 0;
  for (int step = 0; step < NT - 1; ++step) {
    int nxt = cur ^ 1;
    stageA(step + 1, nxt);   // async A prefetch
    loadB(step + 1);         // issue next-tile global loads early (T14)
    compute(cur);            // MFMA on current tile hides the load latency
    packB(nxt);              // cvt+write after compute
    __syncthreads();
    cur = nxt;
  }
  compute(cur);

  const int row4 = (lane >> 4) << 2;
  const int colf = lane & 15;
#pragma unroll
  for (int mf = 0; mf < 4; ++mf) {
    int o = (mblk << 7) + (wr << 6) + (mf << 4) + row4;
    size_t ob = (((size_t)b * MOUT + o) << 12) + nblk * BN + wc * WN + colf;
#pragma unroll
    for (int nf = 0; nf < NF; ++nf) {
      f32x4 v = acc[mf][nf];
      size_t oo = ob + (nf << 4);
      out[oo] = v[0];
      out[oo + 4096] = v[1];
      out[oo + 8192] = v[2];
      out[oo + 12288] = v[3];
    }
  }
}

// ---------------------------------------------------------------------------
// per-(b,ch) mean / rstd over 4096 pixels
// ---------------------------------------------------------------------------
__global__ __launch_bounds__(256) void reduce_mv(const float* __restrict__ x,
                                                 float* __restrict__ mr) {
  int bc = blockIdx.x, t = threadIdx.x;
  const float4* xp = (const float4*)(x + ((size_t)bc << 12));
  float s = 0.f, s2 = 0.f;
  for (int i = t; i < 1024; i += 256) {
    float4 v = xp[i];
    s += v.x + v.y + v.z + v.w;
    s2 += v.x * v.x + v.y * v.y + v.z * v.z + v.w * v.w;
  }
#pragma unroll
  for (int off = 32; off; off >>= 1) {
    s += __shfl_down(s, off);
    s2 += __shfl_down(s2, off);
  }
  __shared__ float ls[4], ls2[4];
  int wid = t >> 6, lane = t & 63;
  if (!lane) { ls[wid] = s; ls2[wid] = s2; }
  __syncthreads();
  if (!t) {
    s = ls[0] + ls[1] + ls[2] + ls[3];
    s2 = ls2[0] + ls2[1] + ls2[2] + ls2[3];
    float m = s * (1.f / 4096.f);
    float var = s2 * (1.f / 4096.f) - m * m;
    mr[2 * bc] = m;
    mr[2 * bc + 1] = rsqrtf(fmaxf(var, 0.f) + IN_EPS);
  }
}

// ---------------------------------------------------------------------------
// out = relu((y - mean)*rstd), float4 over [8*128*4096]
// ---------------------------------------------------------------------------
__global__ __launch_bounds__(256) void finalize_k(const float* __restrict__ y,
                                                  const float* __restrict__ mr,
                                                  float* __restrict__ out) {
  int i = blockIdx.x * 256 + threadIdx.x;
  int bc = i >> 10;
  float m = mr[2 * bc], r = mr[2 * bc + 1];
  float4 v = ((const float4*)y)[i];
  v.x = fmaxf((v.x - m) * r, 0.f);
  v.y = fmaxf((v.y - m) * r, 0.f);
  v.z = fmaxf((v.z - m) * r, 0.f);
  v.w = fmaxf((v.w - m) * r, 0.f);
  ((float4*)out)[i] = v;
}

extern "C" void kernel_launch(void* const* d_in, const int* in_sizes, int n_in,
                              void* d_out, int out_size, void* d_ws,
                              size_t ws_size, hipStream_t stream) {
  (void)in_sizes; (void)n_in; (void)out_size; (void)ws_size;
  const float* feat  = (const float*)d_in[0];
  const float* guide = (const float*)d_in[1];
  const float* pac_w = (const float*)d_in[2];
  const float* dec_w = (const float*)d_in[3];
  // d_in[4] (dec_b): per-channel constant bias cancels in InstanceNorm mean.
  float* out = (float*)d_out;
  char* ws = (char*)d_ws;

  float* kernbuf = (float*)(ws);                 // 8*9*4096*4   = 0x120000
  short* Ws1     = (short*)(ws + 0x120000);      // 2*36*8192*2  = 0x120000
  short* Ws2     = (short*)(ws + 0x240000);      // 1*36*8192*2  = 0x090000
  float* mr1     = (float*)(ws + 0x2D0000);      // 2048*2*4
  float* mr2     = (float*)(ws + 0x2D4000);      // 1024*2*4
  float* pac     = (float*)(ws + 0x300000);      // 8*256*4096*4 = 0x2000000
  float* ybuf    = (float*)(ws + 0x2300000);     // 8*128*4096*4 = 0x1000000

  wconv_k<<<(256 * 2304 + 255) / 256, 256, 0, stream>>>(pac_w, Ws1, 256);
  wconv_k<<<(128 * 2304 + 255) / 256, 256, 0, stream>>>(dec_w, Ws2, 128);
  kern_k<<<dim3(64, 8), 256, 0, stream>>>(guide, kernbuf);

  gemm_conv<2, 128, true, false><<<dim3(32, 2, 8), 512, 0, stream>>>(
      Ws1, feat, kernbuf, nullptr, pac);
  reduce_mv<<<8 * 256, 256, 0, stream>>>(pac, mr1);
  gemm_conv<1, 64, false, true><<<dim3(64, 1, 8), 512, 0, stream>>>(
      Ws2, pac, nullptr, mr1, ybuf);
  reduce_mv<<<8 * 128, 256, 0, stream>>>(ybuf, mr2);
  finalize_k<<<4096, 256, 0, stream>>>(ybuf, mr2, out);
}

// Round 3
// 165.773 us; speedup vs baseline: 3.2926x; 1.6087x over previous
//
#include <hip/hip_runtime.h>
#include <hip/hip_bf16.h>

#define IN_EPS 1e-5f

typedef __attribute__((ext_vector_type(8))) short short8;
typedef __attribute__((ext_vector_type(4))) float f32x4;

__device__ __forceinline__ short f2bf(float f) {
  __hip_bfloat16 h = (__hip_bfloat16)f;   // lowers to v_cvt_pk_bf16_f32
  return *(short*)&h;
}

// ---------------------------------------------------------------------------
// Weight conversion: f32 [O][C][3][3] -> bf16 swizzled panel image.
// Panel p = mblk*36 + cblk*9 + tap holds [o_local 128][c_local 64], elem at
//   (p<<13) + (ol<<6) + (cl ^ ((ol&7)<<3))
// ---------------------------------------------------------------------------
__global__ void wconv_k(const float* __restrict__ src, short* __restrict__ dst,
                        int O) {
  int idx = blockIdx.x * 256 + threadIdx.x;
  if (idx >= O * 2304) return;
  int o = idx / 2304;
  int r = idx - o * 2304;
  int c = r / 9;
  int k = r - c * 9;
  int mblk = o >> 7, ol = o & 127, cb = c >> 6, cl = c & 63;
  dst[(((size_t)(mblk * 36 + cb * 9 + k)) << 13) + (ol << 6) + (cl ^ ((ol & 7) << 3))]
      = f2bf(src[idx]);
}

// ---------------------------------------------------------------------------
// Adaptive Gaussian kernel: kern[b][k][h][w] = exp(-0.5 * sum_c dg^2)
// ---------------------------------------------------------------------------
__global__ __launch_bounds__(256) void kern_k(const float* __restrict__ g,
                                              float* __restrict__ kern) {
  int h = blockIdx.x, b = blockIdx.y;
  int t = threadIdx.x, w = t & 63, cg = t >> 6;
  __shared__ float sm[4][3][66];
  __shared__ float red[4][9][64];
  if (t < 24) {
    int cgi = t / 6, rem = t - cgi * 6, i = rem >> 1, side = rem & 1;
    sm[cgi][i][side ? 65 : 0] = 0.f;
  }
  float acc[9];
#pragma unroll
  for (int k = 0; k < 9; ++k) acc[k] = 0.f;

  for (int cc = 0; cc < 64; ++cc) {
    const float* gp = g + (((size_t)b * 256 + (cg << 6) + cc) << 12) + h * 64 + w;
    sm[cg][0][w + 1] = (h > 0) ? gp[-64] : 0.f;
    sm[cg][1][w + 1] = gp[0];
    sm[cg][2][w + 1] = (h < 63) ? gp[64] : 0.f;
    __syncthreads();
    float ctr = sm[cg][1][w + 1];
#pragma unroll
    for (int i = 0; i < 3; ++i)
#pragma unroll
      for (int j = 0; j < 3; ++j) {
        float d = sm[cg][i][w + j] - ctr;
        acc[i * 3 + j] += d * d;
      }
    __syncthreads();
  }
#pragma unroll
  for (int k = 0; k < 9; ++k) red[cg][k][w] = acc[k];
  __syncthreads();
  for (int idx = t; idx < 576; idx += 256) {
    int k = idx >> 6, w2 = idx & 63;
    float s = red[0][k][w2] + red[1][k][w2] + red[2][k][w2] + red[3][k][w2];
    kern[(((size_t)b * 9 + k) << 12) + h * 64 + w2] = expf(-0.5f * s);
  }
}

// ---------------------------------------------------------------------------
// Implicit-GEMM conv with tap-reuse. BM=128, BN=128 (2 rows), 512 thr/8 waves
// (2M x 4N, wave tile 64x32, acc[4][2]). K order: 4 c-blocks x 9 taps.
// B halo [4 rows][64 cols][64 c] bf16 staged ONCE per c-block (+side array
// for cols -1/64, all-zero); 9 taps read shifted fragments directly.
// GEMM1: per-tap partial accumulated with kern[tap,col] scale (VALU fma).
// GEMM2: direct MFMA accumulation, norm+relu fused in staging.
// A: single-buffered, reg-staged (loads overlap compute, write between
// barriers).
// ---------------------------------------------------------------------------
template <int MBLKS, bool USE_KERN, bool USE_NORM>
__global__ __launch_bounds__(512, 4) void gemm_conv(
    const short* __restrict__ Wimg, const float* __restrict__ X,
    const float* __restrict__ Kf, const float* __restrict__ MRin,
    float* __restrict__ out) {
  constexpr int MOUT = MBLKS * 128;
  __shared__ short ldsA[8192];            // [o 128][c 64] swizzled, 16KB
  __shared__ short ldsB[4 * 64 * 64];     // [r 4][col 64][c 64] swizzled, 32KB
  __shared__ short ldsS[4 * 2 * 64];      // side halo cols (-1,64): zeros, 1KB
  __shared__ float klds[USE_KERN ? 9 * 128 : 1];

  const int t = threadIdx.x;
  const int nblk = blockIdx.x, mblk = blockIdx.y, b = blockIdx.z;
  const int h0 = nblk * 2;
  const int lane = t & 63, wid = t >> 6;
  const int wr = wid >> 2, wc = wid & 3;
  const int fr = lane & 15, kg = (lane >> 4) << 3;
  const int scol = t & 63;        // B staging: image col
  const int c8 = (t >> 6) << 3;   // B staging: 8-channel base

  f32x4 acc[4][2];
#pragma unroll
  for (int i = 0; i < 4; ++i)
#pragma unroll
    for (int j = 0; j < 2; ++j) acc[i][j] = {0.f, 0.f, 0.f, 0.f};

  auto loadA = [&](int step, short8* ar) {
    const short* src = Wimg + (((size_t)(mblk * 36 + step)) << 13) + (t << 3);
    ar[0] = *(const short8*)(src);
    ar[1] = *(const short8*)(src + 4096);
  };
  auto writeA = [&](const short8* ar) {
    *(short8*)&ldsA[t << 3] = ar[0];
    *(short8*)&ldsA[4096 + (t << 3)] = ar[1];
  };
  auto stageB = [&](int cb) {
    int c0 = cb << 6;
    float2 mr[8];
    if (USE_NORM) {
#pragma unroll
      for (int i = 0; i < 8; ++i)
        mr[i] = ((const float2*)MRin)[b * 256 + c0 + c8 + i];
    }
#pragma unroll
    for (int r = 0; r < 4; ++r) {
      int hr = h0 - 1 + r;
      if ((unsigned)hr < 64u) {
        const float* src = X + (((size_t)b * 256 + c0 + c8) << 12) + (hr << 6) + scol;
        short8 pk;
#pragma unroll
        for (int i = 0; i < 8; ++i) {
          float x = src[(size_t)i << 12];
          if (USE_NORM) x = fmaxf((x - mr[i].x) * mr[i].y, 0.f);
          pk[i] = f2bf(x);
        }
        *(short8*)&ldsB[(((r << 6) + scol) << 6) + (c8 ^ ((scol & 7) << 3))] = pk;
      }
    }
  };
  auto computeTap = [&](int tap) {
    const int di = tap / 3 - 1, dj = tap % 3 - 1;
    f32x4 part[4][2];
    if (USE_KERN) {
#pragma unroll
      for (int i = 0; i < 4; ++i)
#pragma unroll
        for (int j = 0; j < 2; ++j) part[i][j] = {0.f, 0.f, 0.f, 0.f};
    }
    f32x4(&dst)[4][2] = *(USE_KERN ? &part : &acc);
#pragma unroll
    for (int ks = 0; ks < 2; ++ks) {
      int kb = (ks << 5) + kg;
      short8 a4[4], b2[2];
#pragma unroll
      for (int mf = 0; mf < 4; ++mf) {
        int rr = (wr << 6) + (mf << 4) + fr;
        a4[mf] = *(const short8*)&ldsA[(rr << 6) + (kb ^ ((rr & 7) << 3))];
      }
#pragma unroll
      for (int nf = 0; nf < 2; ++nf) {
        int px = (wc << 5) + (nf << 4) + fr;
        int rr = (px >> 6) + di + 1;
        int wcol = (px & 63) + dj;
        int kbs = kb ^ ((wcol & 7) << 3);
        const short* pm = &ldsB[(((rr << 6) + wcol) << 6) + kbs];
        const short* ps = &ldsS[(((rr << 1) + (wcol == 64)) << 6) + kbs];
        b2[nf] = *(const short8*)(((unsigned)wcol < 64u) ? pm : ps);
      }
#pragma unroll
      for (int mf = 0; mf < 4; ++mf)
#pragma unroll
        for (int nf = 0; nf < 2; ++nf)
          dst[mf][nf] = __builtin_amdgcn_mfma_f32_16x16x32_bf16(
              a4[mf], b2[nf], dst[mf][nf], 0, 0, 0);
    }
    if (USE_KERN) {
      float kq0 = klds[tap * 128 + (wc << 5) + fr];
      float kq1 = klds[tap * 128 + (wc << 5) + 16 + fr];
#pragma unroll
      for (int mf = 0; mf < 4; ++mf)
#pragma unroll
        for (int j = 0; j < 4; ++j) {
          acc[mf][0][j] += kq0 * part[mf][0][j];
          acc[mf][1][j] += kq1 * part[mf][1][j];
        }
    }
  };

  // ---- prologue: zero halo regions, stage kern / A(0) / B(0) ----
#pragma unroll
  for (int i = 0; i < 4; ++i) {
    short8 z = {0, 0, 0, 0, 0, 0, 0, 0};
    *(short8*)&ldsB[(t << 3) + (i << 12)] = z;
  }
  if (t < 64) {
    short8 z = {0, 0, 0, 0, 0, 0, 0, 0};
    *(short8*)&ldsS[t << 3] = z;
  }
  __syncthreads();
  if (USE_KERN) {
    for (int idx = t; idx < 1152; idx += 512) {
      int tap = idx >> 7, px = idx & 127;
      klds[idx] =
          Kf[(((size_t)b * 9 + tap) << 12) + ((h0 + (px >> 6)) << 6) + (px & 63)];
    }
  }
  {
    short8 ar[2];
    loadA(0, ar);
    writeA(ar);
    stageB(0);
  }
  __syncthreads();

  // ---- main loop: 4 c-blocks x 9 taps ----
  int cb = 0, tap = 0;
  for (int step = 0; step < 36; ++step) {
    short8 ar[2];
    bool more = (step + 1) < 36;
    if (more) loadA(step + 1, ar);   // global->reg, overlaps compute
    computeTap(tap);
    __syncthreads();                 // all waves done reading ldsA/ldsB
    if (more) {
      writeA(ar);
      if (tap == 8) stageB(cb + 1);  // once per 9 taps
      __syncthreads();               // LDS ready for next tap
    }
    if (++tap == 9) { tap = 0; ++cb; }
  }

  // ---- epilogue ----
  const int row4 = (lane >> 4) << 2;
#pragma unroll
  for (int mf = 0; mf < 4; ++mf) {
    int o = (mblk << 7) + (wr << 6) + (mf << 4) + row4;
    size_t ob = (((size_t)b * MOUT + o) << 12) + (nblk << 7) + (wc << 5) + fr;
#pragma unroll
    for (int nf = 0; nf < 2; ++nf) {
      f32x4 v = acc[mf][nf];
      size_t oo = ob + (nf << 4);
      out[oo] = v[0];
      out[oo + 4096] = v[1];
      out[oo + 8192] = v[2];
      out[oo + 12288] = v[3];
    }
  }
}

// ---------------------------------------------------------------------------
// per-(b,ch) mean / rstd over 4096 pixels
// ---------------------------------------------------------------------------
__global__ __launch_bounds__(256) void reduce_mv(const float* __restrict__ x,
                                                 float* __restrict__ mr) {
  int bc = blockIdx.x, t = threadIdx.x;
  const float4* xp = (const float4*)(x + ((size_t)bc << 12));
  float s = 0.f, s2 = 0.f;
  for (int i = t; i < 1024; i += 256) {
    float4 v = xp[i];
    s += v.x + v.y + v.z + v.w;
    s2 += v.x * v.x + v.y * v.y + v.z * v.z + v.w * v.w;
  }
#pragma unroll
  for (int off = 32; off; off >>= 1) {
    s += __shfl_down(s, off);
    s2 += __shfl_down(s2, off);
  }
  __shared__ float ls[4], ls2[4];
  int wid = t >> 6, lane = t & 63;
  if (!lane) { ls[wid] = s; ls2[wid] = s2; }
  __syncthreads();
  if (!t) {
    s = ls[0] + ls[1] + ls[2] + ls[3];
    s2 = ls2[0] + ls2[1] + ls2[2] + ls2[3];
    float m = s * (1.f / 4096.f);
    float var = s2 * (1.f / 4096.f) - m * m;
    mr[2 * bc] = m;
    mr[2 * bc + 1] = rsqrtf(fmaxf(var, 0.f) + IN_EPS);
  }
}

// ---------------------------------------------------------------------------
// out = relu((y - mean)*rstd), float4 over [8*128*4096]
// ---------------------------------------------------------------------------
__global__ __launch_bounds__(256) void finalize_k(const float* __restrict__ y,
                                                  const float* __restrict__ mr,
                                                  float* __restrict__ out) {
  int i = blockIdx.x * 256 + threadIdx.x;
  int bc = i >> 10;
  float m = mr[2 * bc], r = mr[2 * bc + 1];
  float4 v = ((const float4*)y)[i];
  v.x = fmaxf((v.x - m) * r, 0.f);
  v.y = fmaxf((v.y - m) * r, 0.f);
  v.z = fmaxf((v.z - m) * r, 0.f);
  v.w = fmaxf((v.w - m) * r, 0.f);
  ((float4*)out)[i] = v;
}

extern "C" void kernel_launch(void* const* d_in, const int* in_sizes, int n_in,
                              void* d_out, int out_size, void* d_ws,
                              size_t ws_size, hipStream_t stream) {
  (void)in_sizes; (void)n_in; (void)out_size; (void)ws_size;
  const float* feat  = (const float*)d_in[0];
  const float* guide = (const float*)d_in[1];
  const float* pac_w = (const float*)d_in[2];
  const float* dec_w = (const float*)d_in[3];
  // d_in[4] (dec_b): per-channel constant bias cancels in InstanceNorm mean.
  float* out = (float*)d_out;
  char* ws = (char*)d_ws;

  float* kernbuf = (float*)(ws);                 // 8*9*4096*4   = 0x120000
  short* Ws1     = (short*)(ws + 0x120000);      // 2*36*8192*2  = 0x120000
  short* Ws2     = (short*)(ws + 0x240000);      // 1*36*8192*2  = 0x090000
  float* mr1     = (float*)(ws + 0x2D0000);      // 2048*2*4
  float* mr2     = (float*)(ws + 0x2D4000);      // 1024*2*4
  float* pac     = (float*)(ws + 0x300000);      // 8*256*4096*4 = 0x2000000
  float* ybuf    = (float*)(ws + 0x2300000);     // 8*128*4096*4 = 0x1000000

  wconv_k<<<(256 * 2304 + 255) / 256, 256, 0, stream>>>(pac_w, Ws1, 256);
  wconv_k<<<(128 * 2304 + 255) / 256, 256, 0, stream>>>(dec_w, Ws2, 128);
  kern_k<<<dim3(64, 8), 256, 0, stream>>>(guide, kernbuf);

  gemm_conv<2, true, false><<<dim3(32, 2, 8), 512, 0, stream>>>(
      Ws1, feat, kernbuf, nullptr, pac);
  reduce_mv<<<8 * 256, 256, 0, stream>>>(pac, mr1);
  gemm_conv<1, false, true><<<dim3(32, 1, 8), 512, 0, stream>>>(
      Ws2, pac, nullptr, mr1, ybuf);
  reduce_mv<<<8 * 128, 256, 0, stream>>>(ybuf, mr2);
  finalize_k<<<4096, 256, 0, stream>>>(ybuf, mr2, out);
}

// Round 4
// 149.635 us; speedup vs baseline: 3.6477x; 1.1078x over previous
//
#include <hip/hip_runtime.h>
#include <hip/hip_bf16.h>

#define IN_EPS 1e-5f

typedef __attribute__((ext_vector_type(8))) short short8;
typedef __attribute__((ext_vector_type(4))) float f32x4;

__device__ __forceinline__ short f2bf(float f) {
  __hip_bfloat16 h = (__hip_bfloat16)f;   // lowers to v_cvt_pk_bf16_f32
  return *(short*)&h;
}
__device__ __forceinline__ float bf2f(short s) {
  union { unsigned u; float f; } x;
  x.u = ((unsigned)(unsigned short)s) << 16;
  return x.f;
}

// ---------------------------------------------------------------------------
// Weight conversion: f32 [O][C][3][3] -> bf16 swizzled panel image.
// Panel p = mblk*36 + cblk*9 + tap holds [o_local 128][c_local 64], elem at
//   (p<<13) + (ol<<6) + (cl ^ ((ol&7)<<3))
// ---------------------------------------------------------------------------
__global__ void wconv_k(const float* __restrict__ src, short* __restrict__ dst,
                        int O) {
  int idx = blockIdx.x * 256 + threadIdx.x;
  if (idx >= O * 2304) return;
  int o = idx / 2304;
  int r = idx - o * 2304;
  int c = r / 9;
  int k = r - c * 9;
  int mblk = o >> 7, ol = o & 127, cb = c >> 6, cl = c & 63;
  dst[(((size_t)(mblk * 36 + cb * 9 + k)) << 13) + (ol << 6) + (cl ^ ((ol & 7) << 3))]
      = f2bf(src[idx]);
}

// ---------------------------------------------------------------------------
// Adaptive Gaussian kernel: kern[b][k][h][w] = exp(-0.5 * sum_c dg^2)
// One wave = one image row chunk; left/right neighbors via shfl (lane == col).
// No barriers in the channel loop.
// ---------------------------------------------------------------------------
__global__ __launch_bounds__(256) void kern_k(const float* __restrict__ g,
                                              float* __restrict__ kern) {
  int h = blockIdx.x, b = blockIdx.y;
  int t = threadIdx.x, w = t & 63, cg = t >> 6;
  float acc[9];
#pragma unroll
  for (int k = 0; k < 9; ++k) acc[k] = 0.f;
  const float* base = g + (((size_t)b * 256 + (cg << 6)) << 12) + (h << 6) + w;
#pragma unroll 4
  for (int cc = 0; cc < 64; ++cc) {
    const float* gp = base + ((size_t)cc << 12);
    float mid = gp[0];
    float top = (h > 0) ? gp[-64] : 0.f;
    float bot = (h < 63) ? gp[64] : 0.f;
    float rows[3] = {top, mid, bot};
#pragma unroll
    for (int i = 0; i < 3; ++i) {
      float v = rows[i];
      float l = __shfl_up(v, 1);
      float r = __shfl_down(v, 1);
      if (w == 0) l = 0.f;
      if (w == 63) r = 0.f;
      float dl = l - mid, dm = v - mid, dr = r - mid;
      acc[i * 3 + 0] += dl * dl;
      acc[i * 3 + 1] += dm * dm;
      acc[i * 3 + 2] += dr * dr;
    }
  }
  __shared__ float red[4][9][64];
#pragma unroll
  for (int k = 0; k < 9; ++k) red[cg][k][w] = acc[k];
  __syncthreads();
  for (int idx = t; idx < 576; idx += 256) {
    int k = idx >> 6, w2 = idx & 63;
    float s = red[0][k][w2] + red[1][k][w2] + red[2][k][w2] + red[3][k][w2];
    kern[(((size_t)b * 9 + k) << 12) + (h << 6) + w2] = expf(-0.5f * s);
  }
}

// ---------------------------------------------------------------------------
// Implicit-GEMM conv with tap-reuse. BM=128, BN=128|64, 512 thr / 8 waves
// (2M x 4N). K order: 4 c-blocks x 9 taps. B halo [(ROWS+2) rows][64 cols]
// [64 c] bf16 staged once per c-block (T14 split: loads issued before the
// preceding computeTap, written after the barrier). Taps read shifted
// fragments; GEMM1 scales the B fragment by kern[tap,px] (lane-uniform)
// before MFMA. GEMM2 fuses instance-norm+relu into staging.
// ---------------------------------------------------------------------------
template <int MBLKS, int BN, bool USE_KERN, bool USE_NORM>
__global__ __launch_bounds__(512, 4) void gemm_conv(
    const short* __restrict__ Wimg, const float* __restrict__ X,
    const float* __restrict__ Kf, const float* __restrict__ MRin,
    float* __restrict__ out) {
  constexpr int MOUT = MBLKS * 128;
  constexpr int ROWS = BN / 64;     // image rows per tile (2 or 1)
  constexpr int HR = ROWS + 2;      // halo rows
  constexpr int WN = BN / 4;        // N per wave
  constexpr int NF = BN / 64;       // B frags per wave
  __shared__ short ldsA[8192];              // [o 128][c 64] swizzled
  __shared__ short ldsB[HR * 64 * 64];      // [r][col 64][c 64] swizzled
  __shared__ short ldsS[HR * 2 * 64];       // side halo cols (-1,64): zeros
  __shared__ float klds[USE_KERN ? 9 * BN : 1];

  const int t = threadIdx.x;
  const int nblk = blockIdx.x, mblk = blockIdx.y, b = blockIdx.z;
  const int h0 = nblk * ROWS;
  const int lane = t & 63, wid = t >> 6;
  const int wr = wid >> 2, wc = wid & 3;
  const int fr = lane & 15, kg = (lane >> 4) << 3;
  const int scol = t & 63;        // B staging: image col
  const int c8 = (t >> 6) << 3;   // B staging: 8-channel base

  f32x4 acc[4][NF];
#pragma unroll
  for (int i = 0; i < 4; ++i)
#pragma unroll
    for (int j = 0; j < NF; ++j) acc[i][j] = {0.f, 0.f, 0.f, 0.f};

  float breg[HR][8];
  float2 mreg[8];

  auto loadA = [&](int step, short8* ar) {
    const short* src = Wimg + (((size_t)(mblk * 36 + step)) << 13) + (t << 3);
    ar[0] = *(const short8*)(src);
    ar[1] = *(const short8*)(src + 4096);
  };
  auto writeA = [&](const short8* ar) {
    *(short8*)&ldsA[t << 3] = ar[0];
    *(short8*)&ldsA[4096 + (t << 3)] = ar[1];
  };
  auto loadBregs = [&](int cbn) {
    int c0 = cbn << 6;
    const float* base = X + (((size_t)b * 256 + c0 + c8) << 12) + scol;
    if (USE_NORM) {
#pragma unroll
      for (int i = 0; i < 8; ++i)
        mreg[i] = ((const float2*)MRin)[b * 256 + c0 + c8 + i];
    }
#pragma unroll
    for (int r = 0; r < HR; ++r) {
      int hr = h0 - 1 + r;
      bool okr = (unsigned)hr < 64u;
      const float* src = base + (hr << 6);
#pragma unroll
      for (int i = 0; i < 8; ++i)
        breg[r][i] = okr ? src[(size_t)i << 12] : 0.f;
    }
  };
  auto writeB = [&]() {
#pragma unroll
    for (int r = 0; r < HR; ++r) {
      short8 pk;
#pragma unroll
      for (int i = 0; i < 8; ++i) {
        float x = breg[r][i];
        if (USE_NORM) x = fmaxf((x - mreg[i].x) * mreg[i].y, 0.f);
        pk[i] = f2bf(x);
      }
      *(short8*)&ldsB[(((r << 6) + scol) << 6) + (c8 ^ ((scol & 7) << 3))] = pk;
    }
  };
  auto computeTap = [&](int tap) {
    const int di = tap / 3 - 1, dj = tap % 3 - 1;
    float kfv[NF];
    if (USE_KERN) {
#pragma unroll
      for (int nf = 0; nf < NF; ++nf)
        kfv[nf] = klds[tap * BN + wc * WN + (nf << 4) + fr];
    }
#pragma unroll
    for (int ks = 0; ks < 2; ++ks) {
      int kb = (ks << 5) + kg;
      short8 a4[4], b2[NF];
#pragma unroll
      for (int mf = 0; mf < 4; ++mf) {
        int rr = (wr << 6) + (mf << 4) + fr;
        a4[mf] = *(const short8*)&ldsA[(rr << 6) + (kb ^ ((rr & 7) << 3))];
      }
#pragma unroll
      for (int nf = 0; nf < NF; ++nf) {
        int px = wc * WN + (nf << 4) + fr;
        int rr2 = (px >> 6) + di + 1;
        int wcol = (px & 63) + dj;
        int kbs = kb ^ ((wcol & 7) << 3);
        const short* pm = &ldsB[(((rr2 << 6) + wcol) << 6) + kbs];
        const short* ps = &ldsS[(((rr2 << 1) + (wcol == 64)) << 6) + kbs];
        short8 bb = *(const short8*)(((unsigned)wcol < 64u) ? pm : ps);
        if (USE_KERN) {
#pragma unroll
          for (int i = 0; i < 8; ++i) bb[i] = f2bf(bf2f(bb[i]) * kfv[nf]);
        }
        b2[nf] = bb;
      }
#pragma unroll
      for (int mf = 0; mf < 4; ++mf)
#pragma unroll
        for (int nf = 0; nf < NF; ++nf)
          acc[mf][nf] = __builtin_amdgcn_mfma_f32_16x16x32_bf16(
              a4[mf], b2[nf], acc[mf][nf], 0, 0, 0);
    }
  };

  // ---- prologue ----
  if (t < HR * 16) {
    short8 z = {0, 0, 0, 0, 0, 0, 0, 0};
    *(short8*)&ldsS[t << 3] = z;
  }
  if (USE_KERN) {
    for (int idx = t; idx < 9 * BN; idx += 512) {
      int tap = idx / BN, px = idx & (BN - 1);
      klds[idx] = Kf[(((size_t)b * 9 + tap) << 12) +
                     ((h0 + (px >> 6)) << 6) + (px & 63)];
    }
  }
  {
    short8 ar[2];
    loadA(0, ar);
    loadBregs(0);
    writeA(ar);
    writeB();
  }
  __syncthreads();

  // ---- main loop: 4 c-blocks x 9 taps ----
  int cb = 0, tap = 0;
  for (int step = 0; step < 36; ++step) {
    bool more = (step + 1) < 36;
    bool lastTap = (tap == 8);
    short8 ar[2];
    if (more) loadA(step + 1, ar);            // global->reg, overlaps compute
    if (more && lastTap) loadBregs(cb + 1);   // T14: issue early
    computeTap(tap);
    __syncthreads();                          // all waves done reading LDS
    if (more) {
      writeA(ar);
      if (lastTap) writeB();                  // cvt+norm+write after barrier
      __syncthreads();
    }
    if (++tap == 9) { tap = 0; ++cb; }
  }

  // ---- epilogue ----
  const int row4 = (lane >> 4) << 2;
#pragma unroll
  for (int mf = 0; mf < 4; ++mf) {
    int o = (mblk << 7) + (wr << 6) + (mf << 4) + row4;
    size_t ob = (((size_t)b * MOUT + o) << 12) + nblk * BN + wc * WN + fr;
#pragma unroll
    for (int nf = 0; nf < NF; ++nf) {
      f32x4 v = acc[mf][nf];
      size_t oo = ob + (nf << 4);
      out[oo] = v[0];
      out[oo + 4096] = v[1];
      out[oo + 8192] = v[2];
      out[oo + 12288] = v[3];
    }
  }
}

// ---------------------------------------------------------------------------
// per-(b,ch) mean / rstd over 4096 pixels
// ---------------------------------------------------------------------------
__global__ __launch_bounds__(256) void reduce_mv(const float* __restrict__ x,
                                                 float* __restrict__ mr) {
  int bc = blockIdx.x, t = threadIdx.x;
  const float4* xp = (const float4*)(x + ((size_t)bc << 12));
  float s = 0.f, s2 = 0.f;
  for (int i = t; i < 1024; i += 256) {
    float4 v = xp[i];
    s += v.x + v.y + v.z + v.w;
    s2 += v.x * v.x + v.y * v.y + v.z * v.z + v.w * v.w;
  }
#pragma unroll
  for (int off = 32; off; off >>= 1) {
    s += __shfl_down(s, off);
    s2 += __shfl_down(s2, off);
  }
  __shared__ float ls[4], ls2[4];
  int wid = t >> 6, lane = t & 63;
  if (!lane) { ls[wid] = s; ls2[wid] = s2; }
  __syncthreads();
  if (!t) {
    s = ls[0] + ls[1] + ls[2] + ls[3];
    s2 = ls2[0] + ls2[1] + ls2[2] + ls2[3];
    float m = s * (1.f / 4096.f);
    float var = s2 * (1.f / 4096.f) - m * m;
    mr[2 * bc] = m;
    mr[2 * bc + 1] = rsqrtf(fmaxf(var, 0.f) + IN_EPS);
  }
}

// ---------------------------------------------------------------------------
// out = relu((y - mean)*rstd), float4 over [8*128*4096]
// ---------------------------------------------------------------------------
__global__ __launch_bounds__(256) void finalize_k(const float* __restrict__ y,
                                                  const float* __restrict__ mr,
                                                  float* __restrict__ out) {
  int i = blockIdx.x * 256 + threadIdx.x;
  int bc = i >> 10;
  float m = mr[2 * bc], r = mr[2 * bc + 1];
  float4 v = ((const float4*)y)[i];
  v.x = fmaxf((v.x - m) * r, 0.f);
  v.y = fmaxf((v.y - m) * r, 0.f);
  v.z = fmaxf((v.z - m) * r, 0.f);
  v.w = fmaxf((v.w - m) * r, 0.f);
  ((float4*)out)[i] = v;
}

extern "C" void kernel_launch(void* const* d_in, const int* in_sizes, int n_in,
                              void* d_out, int out_size, void* d_ws,
                              size_t ws_size, hipStream_t stream) {
  (void)in_sizes; (void)n_in; (void)out_size; (void)ws_size;
  const float* feat  = (const float*)d_in[0];
  const float* guide = (const float*)d_in[1];
  const float* pac_w = (const float*)d_in[2];
  const float* dec_w = (const float*)d_in[3];
  // d_in[4] (dec_b): per-channel constant bias cancels in InstanceNorm mean.
  float* out = (float*)d_out;
  char* ws = (char*)d_ws;

  float* kernbuf = (float*)(ws);                 // 8*9*4096*4   = 0x120000
  short* Ws1     = (short*)(ws + 0x120000);      // 2*36*8192*2  = 0x120000
  short* Ws2     = (short*)(ws + 0x240000);      // 1*36*8192*2  = 0x090000
  float* mr1     = (float*)(ws + 0x2D0000);      // 2048*2*4
  float* mr2     = (float*)(ws + 0x2D4000);      // 1024*2*4
  float* pac     = (float*)(ws + 0x300000);      // 8*256*4096*4 = 0x2000000
  float* ybuf    = (float*)(ws + 0x2300000);     // 8*128*4096*4 = 0x1000000

  wconv_k<<<(256 * 2304 + 255) / 256, 256, 0, stream>>>(pac_w, Ws1, 256);
  wconv_k<<<(128 * 2304 + 255) / 256, 256, 0, stream>>>(dec_w, Ws2, 128);
  kern_k<<<dim3(64, 8), 256, 0, stream>>>(guide, kernbuf);

  gemm_conv<2, 128, true, false><<<dim3(32, 2, 8), 512, 0, stream>>>(
      Ws1, feat, kernbuf, nullptr, pac);
  reduce_mv<<<8 * 256, 256, 0, stream>>>(pac, mr1);
  gemm_conv<1, 64, false, true><<<dim3(64, 1, 8), 512, 0, stream>>>(
      Ws2, pac, nullptr, mr1, ybuf);
  reduce_mv<<<8 * 128, 256, 0, stream>>>(ybuf, mr2);
  finalize_k<<<4096, 256, 0, stream>>>(ybuf, mr2, out);
}